// Round 6
// baseline (348.054 us; speedup 1.0000x reference)
//
#include <hip/hip_runtime.h>

// ROUND 6 = MEASUREMENT ROUND (differential, like R3 which resolved kernel=68us).
// Question: can this kernel's store pattern alone sustain fill-kernel BW?
//   launch store_only, store_only, full   (full is LAST -> output correct)
//   SO = (dur_us - 204.5 - 65) / 2
// SO~43 -> store path fine, residual is hot-loop serialization (attack schedule).
// SO~60 -> store path is the limiter under this config (attack store stream).

#define B_N   8
#define S_N   2048
#define K_N   21
#define L_N   16
#define CM_N  256
#define SCHUNK 128
#define CHUNKS (S_N / SCHUNK)   // 16
#define LGRP   2
#define NLG    (L_N / LGRP)      // 8
#define WSTRIDE 260

typedef float vfloat4 __attribute__((ext_vector_type(4)));

__device__ __forceinline__ void stage_wt(float (*wt)[WSTRIDE],
                                         const float* __restrict__ W,
                                         int l, int tid) {
    const vfloat4* wb4 = (const vfloat4*)(W + (size_t)l * CM_N * K_N);
    for (int i4 = tid; i4 < CM_N * K_N / 4; i4 += 256) {
        vfloat4 v = wb4[i4];
        int e0 = i4 * 4;
#pragma unroll
        for (int j = 0; j < 4; ++j) {
            int e = e0 + j;
            int c = e / K_N, k = e - c * K_N;
            wt[k][c] = v[j];
        }
    }
}

// ---------------- store-only ceiling probe ----------------
// Identical grid/block/launch_bounds, identical out addressing per iteration,
// identical LDS footprint (pins 4 blocks/CU like the real kernel). No x/W
// loads, no LDS reads, no FMAs: pure store stream.
__global__ __launch_bounds__(256, 4) void store_only_kernel(
    const float* __restrict__ bias,
    float* __restrict__ out)
{
    __shared__ float pad[SCHUNK * 24 + K_N * WSTRIDE];  // same 34.1 KB as real kernel
    ((volatile float*)pad)[threadIdx.x] = 0.f;          // keep allocation live
    __syncthreads();

    const int tid   = threadIdx.x;
    const int bx    = blockIdx.x;
    const int chunk = bx % CHUNKS;
    const int lg    = (bx / CHUNKS) % NLG;
    const int b     = bx / (CHUNKS * NLG);
    const int s0    = chunk * SCHUNK;
    const int l0    = lg * LGRP;

    const int lane = tid & 63;
    const int wave = tid >> 6;
    const int c0   = lane * 4;

    for (int pass = 0; pass < LGRP; ++pass) {
        const int l = l0 + pass;
        vfloat4 bv = *(const vfloat4*)(bias + (size_t)l * CM_N + c0);
        float* outbase = out + (((size_t)b * L_N + l) * S_N + s0) * CM_N + c0;
        for (int i = 0; i < SCHUNK / 4; ++i) {
            const int r = i * 4 + wave;
            *(vfloat4*)(outbase + (size_t)r * CM_N) = bv;   // junk; full kernel overwrites
        }
    }
}

// ---------------- real kernel (byte-identical to round 5) ----------------
__global__ __launch_bounds__(256, 4) void pssm_proj_kernel(
    const float* __restrict__ x,     // [B,S,K]
    const float* __restrict__ W,     // [L,CM,K]
    const float* __restrict__ bias,  // [L,CM]
    float* __restrict__ out)         // [B,L,S,CM]
{
    __shared__ float xs[SCHUNK][24];
    __shared__ float wt[K_N][WSTRIDE];

    const int tid   = threadIdx.x;
    const int bx    = blockIdx.x;
    const int chunk = bx % CHUNKS;
    const int lg    = (bx / CHUNKS) % NLG;
    const int b     = bx / (CHUNKS * NLG);
    const int s0    = chunk * SCHUNK;
    const int l0    = lg * LGRP;

    const vfloat4* xb4 = (const vfloat4*)(x + ((size_t)b * S_N + s0) * K_N);
    for (int i4 = tid; i4 < SCHUNK * K_N / 4; i4 += 256) {
        vfloat4 v = xb4[i4];
        int e0 = i4 * 4;
#pragma unroll
        for (int j = 0; j < 4; ++j) {
            int e = e0 + j;
            int r = e / K_N, k = e - r * K_N;
            xs[r][k] = v[j];
        }
    }

    stage_wt(wt, W, l0, tid);
    __syncthreads();

    const int lane = tid & 63;
    const int wave = tid >> 6;
    const int c0   = lane * 4;

    vfloat4 wfv[K_N];
#pragma unroll
    for (int k = 0; k < K_N; ++k)
        wfv[k] = *(const vfloat4*)(&wt[k][c0]);

    __syncthreads();
    stage_wt(wt, W, l0 + 1, tid);   // stage B under pass A's stream

    vfloat4 bv = *(const vfloat4*)(bias + (size_t)l0 * CM_N + c0);

    for (int pass = 0; pass < LGRP; ++pass) {
        const int l = l0 + pass;
        float* outbase = out + (((size_t)b * L_N + l) * S_N + s0) * CM_N + c0;

        for (int i = 0; i < SCHUNK / 4; ++i) {
            const int r = i * 4 + wave;
            const vfloat4* xv = (const vfloat4*)(&xs[r][0]);

            float a0 = bv.x, a1 = bv.y, a2 = bv.z, a3 = bv.w;
#pragma unroll
            for (int kb = 0; kb < 6; ++kb) {
                vfloat4 xq = xv[kb];
                float xe[4] = {xq.x, xq.y, xq.z, xq.w};
#pragma unroll
                for (int e = 0; e < 4; ++e) {
                    const int k = kb * 4 + e;
                    if (k < K_N) {
                        a0 += xe[e] * wfv[k].x;
                        a1 += xe[e] * wfv[k].y;
                        a2 += xe[e] * wfv[k].z;
                        a3 += xe[e] * wfv[k].w;
                    }
                }
            }

            vfloat4 o = {a0, a1, a2, a3};
            *(vfloat4*)(outbase + (size_t)r * CM_N) = o;
        }

        if (pass == 0) {
            __syncthreads();
#pragma unroll
            for (int k = 0; k < K_N; ++k)
                wfv[k] = *(const vfloat4*)(&wt[k][c0]);
            bv = *(const vfloat4*)(bias + (size_t)(l0 + 1) * CM_N + c0);
        }
    }
}

extern "C" void kernel_launch(void* const* d_in, const int* in_sizes, int n_in,
                              void* d_out, int out_size, void* d_ws, size_t ws_size,
                              hipStream_t stream) {
    const float* x    = (const float*)d_in[0];
    const float* W    = (const float*)d_in[1];
    const float* bias = (const float*)d_in[2];
    float* out        = (float*)d_out;

    dim3 grid(B_N * NLG * CHUNKS);   // 1024 blocks = 4/CU
    dim3 block(256);
    // 2x store-only probe (junk values), then the real kernel LAST so every
    // output element is overwritten with correct values.
    store_only_kernel<<<grid, block, 0, stream>>>(bias, out);
    store_only_kernel<<<grid, block, 0, stream>>>(bias, out);
    pssm_proj_kernel<<<grid, block, 0, stream>>>(x, W, bias, out);
}

// Round 7
// 273.770 us; speedup vs baseline: 1.2713x; 1.2713x over previous
//
#include <hip/hip_runtime.h>

// Round 7: kill the LDS broadcast convoy with v_readlane.
// R6 measured: store-only = 39.3us (= fill floor), full kernel = 65us ->
// residual is hot-loop serialization. The 6x wave-uniform ds_read_b128 per
// row (12cyc each for 16 useful bytes, anti-phased with the FMA burst across
// lockstep waves) was the LDS-pipe convoy. Now: each wave owns 32 CONTIGUOUS
// rows; lane L holds row (L&31)'s full 21-float x in VGPRs (one-time load);
// the hot loop broadcasts row r via v_readlane (VALU pipe, SGPR operand to
// v_fma) -> hot-loop LDS traffic = 0, stores become the only limiter.

#define B_N   8
#define S_N   2048
#define K_N   21
#define L_N   16
#define CM_N  256
#define SCHUNK 128
#define CHUNKS (S_N / SCHUNK)   // 16
#define LGRP   2                 // layers per block, time-multiplexed
#define NLG    (L_N / LGRP)      // 8
#define WSTRIDE 260              // 1040B rows: 16B-aligned, bank-spread

typedef float vfloat4 __attribute__((ext_vector_type(4)));

__device__ __forceinline__ float bcast_lane(float v, int lane) {
    return __int_as_float(__builtin_amdgcn_readlane(__float_as_int(v), lane));
}

__device__ __forceinline__ void stage_wt(float (*wt)[WSTRIDE],
                                         const float* __restrict__ W,
                                         int l, int tid) {
    const vfloat4* wb4 = (const vfloat4*)(W + (size_t)l * CM_N * K_N);
    for (int i4 = tid; i4 < CM_N * K_N / 4; i4 += 256) {
        vfloat4 v = wb4[i4];
        int e0 = i4 * 4;
#pragma unroll
        for (int j = 0; j < 4; ++j) {
            int e = e0 + j;
            int c = e / K_N, k = e - c * K_N;
            wt[k][c] = v[j];
        }
    }
}

// LDS: 10.5KB (xs flat) + 21.8KB (wt) = 32.3KB -> 4 blocks/CU.
__global__ __launch_bounds__(256, 4) void pssm_proj_kernel(
    const float* __restrict__ x,     // [B,S,K]
    const float* __restrict__ W,     // [L,CM,K]
    const float* __restrict__ bias,  // [L,CM]
    float* __restrict__ out)         // [B,L,S,CM]
{
    __shared__ float xs[SCHUNK * K_N];      // flat, stride-21 rows
    __shared__ float wt[K_N][WSTRIDE];

    const int tid   = threadIdx.x;
    const int bx    = blockIdx.x;
    const int chunk = bx % CHUNKS;
    const int lg    = (bx / CHUNKS) % NLG;
    const int b     = bx / (CHUNKS * NLG);
    const int s0    = chunk * SCHUNK;
    const int l0    = lg * LGRP;

    // ---- stage x chunk -> LDS: straight flat copy, dwordx4 both sides ----
    const vfloat4* xb4 = (const vfloat4*)(x + ((size_t)b * S_N + s0) * K_N);
    vfloat4* xs4 = (vfloat4*)xs;
    for (int i4 = tid; i4 < SCHUNK * K_N / 4; i4 += 256)
        xs4[i4] = xb4[i4];

    stage_wt(wt, W, l0, tid);      // layer A weights
    __syncthreads();

    const int lane = tid & 63;
    const int wave = tid >> 6;
    const int c0   = lane * 4;

    // ---- pass A fragment: 21 conflict-free ds_read_b128 ----
    vfloat4 wfv[K_N];
#pragma unroll
    for (int k = 0; k < K_N; ++k)
        wfv[k] = *(const vfloat4*)(&wt[k][c0]);

    // ---- x slab -> registers: lane L holds row (L&31) of this wave's
    // 32 contiguous rows. 21 ds_read_b32, stride 21 dwords: gcd(21,32)=1
    // -> all 32 banks, upper lanes same-address (free broadcast). Once per
    // block; feeds BOTH layer passes. ----
    float xsl[K_N];
    const float* slab = xs + (wave * 32 + (lane & 31)) * K_N;
#pragma unroll
    for (int k = 0; k < K_N; ++k)
        xsl[k] = slab[k];

    __syncthreads();               // wt reusable
    stage_wt(wt, W, l0 + 1, tid);  // stage B under pass A's stream

    vfloat4 bv = *(const vfloat4*)(bias + (size_t)l0 * CM_N + c0);

    for (int pass = 0; pass < LGRP; ++pass) {
        const int l = l0 + pass;
        // wave's rows are contiguous: s0 + wave*32 + r
        float* outbase = out + (((size_t)b * L_N + l) * S_N + s0 + wave * 32) * CM_N + c0;

        for (int r = 0; r < 32; ++r) {
            float a0 = bv.x, a1 = bv.y, a2 = bv.z, a3 = bv.w;
#pragma unroll
            for (int k = 0; k < K_N; ++k) {
                const float xk = bcast_lane(xsl[k], r);   // VALU broadcast, no LDS
                a0 += xk * wfv[k].x;
                a1 += xk * wfv[k].y;
                a2 += xk * wfv[k].z;
                a3 += xk * wfv[k].w;
            }
            vfloat4 o = {a0, a1, a2, a3};
            *(vfloat4*)(outbase + (size_t)r * CM_N) = o;   // 1KB coalesced
        }

        if (pass == 0) {
            __syncthreads();       // wt[B] staged by all waves
#pragma unroll
            for (int k = 0; k < K_N; ++k)
                wfv[k] = *(const vfloat4*)(&wt[k][c0]);
            bv = *(const vfloat4*)(bias + (size_t)(l0 + 1) * CM_N + c0);
        }
    }
}

extern "C" void kernel_launch(void* const* d_in, const int* in_sizes, int n_in,
                              void* d_out, int out_size, void* d_ws, size_t ws_size,
                              hipStream_t stream) {
    const float* x    = (const float*)d_in[0];
    const float* W    = (const float*)d_in[1];
    const float* bias = (const float*)d_in[2];
    float* out        = (float*)d_out;

    dim3 grid(B_N * NLG * CHUNKS);   // 1024 blocks = exactly 4/CU, one round
    dim3 block(256);
    pssm_proj_kernel<<<grid, block, 0, stream>>>(x, W, bias, out);
}